// Round 7
// baseline (1877.148 us; speedup 1.0000x reference)
//
#include <hip/hip_runtime.h>
#include <hip/hip_bf16.h>
#include <cstdint>
#include <cstddef>

typedef float  f32x4  __attribute__((ext_vector_type(4)));
typedef __bf16 bf16x8 __attribute__((ext_vector_type(8)));

#define LOG2E 1.4426950408889634f

static constexpr int GN   = 8192;   // nodes
static constexpr int GIN  = 512;    // in features
static constexpr int GOUT = 256;    // out features

// ---------------- async global->LDS (width 16) ----------------
static __device__ __forceinline__ void gload_lds16(const void* g, void* lds){
  typedef uint32_t __attribute__((address_space(1)))* gp_t;
  typedef uint32_t __attribute__((address_space(3)))* lp_t;
  __builtin_amdgcn_global_load_lds((gp_t)(uintptr_t)g,
                                   (lp_t)(uint32_t)(uintptr_t)lds, 16, 0, 0);
}

// ---------------- prep kernels ----------------
// wal/war = (W @ a_{l,r}) * log2(e)  AND  WT[c][k] = bf16(W[k][c]). 512 blocks x 64.
__global__ void k_wprep(const float* __restrict__ W, const float* __restrict__ al,
                        const float* __restrict__ ar, float* __restrict__ wal,
                        float* __restrict__ war, __bf16* __restrict__ WT){
  int k = blockIdx.x;
  int lane = threadIdx.x;
  float4 wv = ((const float4*)(W + (size_t)k*GOUT))[lane];
  float4 av = ((const float4*)al)[lane];
  float4 bv = ((const float4*)ar)[lane];
  WT[(size_t)(lane*4+0)*GIN + k] = (__bf16)wv.x;
  WT[(size_t)(lane*4+1)*GIN + k] = (__bf16)wv.y;
  WT[(size_t)(lane*4+2)*GIN + k] = (__bf16)wv.z;
  WT[(size_t)(lane*4+3)*GIN + k] = (__bf16)wv.w;
  float sl = wv.x*av.x + wv.y*av.y + wv.z*av.z + wv.w*av.w;
  float sr = wv.x*bv.x + wv.y*bv.y + wv.z*bv.z + wv.w*bv.w;
  #pragma unroll
  for(int o=32;o;o>>=1){ sl += __shfl_down(sl,o,64); sr += __shfl_down(sr,o,64); }
  if(lane==0){ wal[k] = sl*LOG2E; war[k] = sr*LOG2E; }
}

// fused: hb = bf16(h); Wh1/Wh2 fp32 row-dots. 4 rows/block.
__global__ void k_prep_h(const float* __restrict__ h, const float* __restrict__ wal,
                         const float* __restrict__ war, __bf16* __restrict__ hb,
                         float* __restrict__ Wh1, float* __restrict__ Wh2){
  int row = blockIdx.x*4 + (threadIdx.x>>6);
  int lane = threadIdx.x & 63;
  const float4* hp = (const float4*)(h + (size_t)row*GIN);
  float4 v0 = hp[lane*2], v1 = hp[lane*2+1];
  bf16x8 o;
  o[0]=(__bf16)v0.x; o[1]=(__bf16)v0.y; o[2]=(__bf16)v0.z; o[3]=(__bf16)v0.w;
  o[4]=(__bf16)v1.x; o[5]=(__bf16)v1.y; o[6]=(__bf16)v1.z; o[7]=(__bf16)v1.w;
  *(bf16x8*)(hb + (size_t)row*GIN + lane*8) = o;
  float4 a0 = ((const float4*)wal)[lane*2], a1 = ((const float4*)wal)[lane*2+1];
  float4 b0 = ((const float4*)war)[lane*2], b1 = ((const float4*)war)[lane*2+1];
  float sl = v0.x*a0.x+v0.y*a0.y+v0.z*a0.z+v0.w*a0.w
           + v1.x*a1.x+v1.y*a1.y+v1.z*a1.z+v1.w*a1.w;
  float sr = v0.x*b0.x+v0.y*b0.y+v0.z*b0.z+v0.w*b0.w
           + v1.x*b1.x+v1.y*b1.y+v1.z*b1.z+v1.w*b1.w;
  #pragma unroll
  for(int of=32;of;of>>=1){ sl += __shfl_down(sl,of,64); sr += __shfl_down(sr,of,64); }
  if(lane==0){ Wh1[row]=sl; Wh2[row]=sr; }
}

// ---------------- GEMM: WhbT[m][n] = sum_k WT[m][k]*hb[n][k]  (= (h@W)^T, bf16)
__global__ __launch_bounds__(256,1) void k_gemmT(const __bf16* __restrict__ WT,
                                                 const __bf16* __restrict__ hb,
                                                 __bf16* __restrict__ WhbT){
  __shared__ __attribute__((aligned(16))) __bf16 As[2][64*64];
  __shared__ __attribute__((aligned(16))) __bf16 Bs[2][128*64];
  const int tid = threadIdx.x, lane = tid & 63, w = tid >> 6;
  const int mb = blockIdx.x >> 6, nb = blockIdx.x & 63;
  const int m0 = mb*64, n0 = nb*128;

  f32x4 acc[8];
  #pragma unroll
  for(int t=0;t<8;t++) acc[t] = (f32x4){0.f,0.f,0.f,0.f};

  const int lr = lane>>3;
  const int bs_sw = ((lane&7)*16) ^ (lr<<4);

  auto stage = [&](int it, int buf){
    const int k0b = it*128;
    #pragma unroll
    for(int s=0;s<6;s++){
      int u = w + s*4;
      const char* src; char* dst;
      if(u < 8){
        int r8 = u*8;
        src = (const char*)(WT + (size_t)(m0 + r8 + lr)*GIN);
        dst = (char*)&As[buf][0] + r8*128;
      } else {
        int r8 = (u-8)*8;
        src = (const char*)(hb + (size_t)(n0 + r8 + lr)*GIN);
        dst = (char*)&Bs[buf][0] + r8*128;
      }
      gload_lds16(src + k0b + bs_sw, dst);
    }
  };

  auto kstep = [&](int kk, int buf){
    const int ko = kk*64 + (lane>>4)*16;
    const int am = 16*w + (lane&15);
    bf16x8 af = *(const bf16x8*)((const char*)&As[buf][0] + am*128 + (ko ^ ((am&7)<<4)));
    #pragma unroll
    for(int t=0;t<8;t++){
      int n = 16*t + (lane&15);
      bf16x8 bf = *(const bf16x8*)((const char*)&Bs[buf][0] + n*128 + (ko ^ ((n&7)<<4)));
      acc[t] = __builtin_amdgcn_mfma_f32_16x16x32_bf16(af, bf, acc[t], 0, 0, 0);
    }
  };

  stage(0,0);
  asm volatile("s_waitcnt vmcnt(0)" ::: "memory");
  __builtin_amdgcn_s_barrier();
  for(int it=0; it<8; it++){
    int buf = it & 1;
    if(it < 7) stage(it+1, buf^1);
    kstep(0, buf);
    kstep(1, buf);
    asm volatile("s_waitcnt vmcnt(0)" ::: "memory");
    __builtin_amdgcn_s_barrier();
  }

  const int mrow = m0 + 16*w + 4*(lane>>4);
  const int nc0  = n0 + (lane&15);
  #pragma unroll
  for(int t=0;t<8;t++){
    #pragma unroll
    for(int r=0;r<4;r++){
      WhbT[(size_t)(mrow + r)*GN + nc0 + 16*t] = (__bf16)acc[t][r];
    }
  }
}

// ---------------- fused masked-softmax-attention (depth-2 adj pipeline) ----------
// grid 512: rg=bid>>3 (64 rowgroups of 128), chunk=bid&7 (1024 cols)
// block 256 thr / 4 waves; wave owns rows +0..15 and +64..79 (2 MFMA sets).
// Two adj register sets A/B (statically indexed). At half h:
//   stage(h+1) -> adj_pack(set h&1; its loads were force-retired at bottom of h-1:
//   ZERO wait here) -> adj_load(h+2 into same set) -> MFMAs -> vmcnt(32)
//   (retires exactly adj(h+1)+stage(h+1) = 40 oldest) -> barrier.
// Every adj batch gets ~2 half-periods to land; >=32 loads/wave stay outstanding
// continuously -> HBM stays fed through the bottom wait.
template<bool PART>
__global__ __launch_bounds__(256,2) void k_attn(const int* __restrict__ adj,
                                                const __bf16* __restrict__ WhbT,
                                                const float* __restrict__ Wh1s,
                                                const float* __restrict__ Wh2s,
                                                float* __restrict__ pv_out,
                                                float* __restrict__ s_out){
  __shared__ __attribute__((aligned(16))) __bf16 Vs[2][256*64];
  const int tid = threadIdx.x, lane = tid & 63, w = tid >> 6;
  const int rg = blockIdx.x >> 3, chunk = blockIdx.x & 7;
  const int r0 = rg * 128;
  const int j0 = chunk * 1024;

  f32x4 acc0[16], acc1[16];
  #pragma unroll
  for(int t=0;t<16;t++){ acc0[t] = (f32x4){0.f,0.f,0.f,0.f}; acc1[t] = (f32x4){0.f,0.f,0.f,0.f}; }
  f32x4 accs0 = (f32x4){0.f,0.f,0.f,0.f};
  f32x4 accs1 = (f32x4){0.f,0.f,0.f,0.f};

  bf16x8 ones;
  #pragma unroll
  for(int j=0;j<8;j++) ones[j] = (__bf16)1.0f;

  const int kg  = lane >> 4;
  const int kg8 = kg << 3;
  const int myrow0 = r0 + 16*w + (lane & 15);
  const float wh1_0 = Wh1s[myrow0];                 // pre-scaled by log2(e)
  const float wh1_1 = Wh1s[myrow0 + 64];
  const float* wh2p = Wh2s + j0 + kg8;

  const size_t arow0 = (size_t)(r0 + 16*w) * GN + j0;
  const size_t arow1 = arow0 + (size_t)64 * GN;

  const int lr = lane>>3;
  const int bs_sw = ((lane&7)*16) ^ (lr<<4);

  auto stage = [&](int it, int buf){
    const int colb = (j0 + it*64)*2;
    #pragma unroll
    for(int s=0;s<8;s++){
      int u = w + s*4;
      int r8 = u*8;
      const char* src = (const char*)WhbT + (size_t)(r8 + lr)*(GN*2) + colb + bs_sw;
      gload_lds16(src, (char*)&Vs[buf][0] + r8*128);
    }
  };

  // two adj register sets (explicit, statically indexed)
  int aA0[16], aA1[16], aB0[16], aB1[16];
  auto adj_load = [&](int tt, int (&p0)[16], int (&p1)[16]){
    const int co = tt*64 + lane;
    #pragma unroll
    for(int r=0;r<16;r++) p0[r] = adj[arow0 + (size_t)r*GN + co];
    #pragma unroll
    for(int r=0;r<16;r++) p1[r] = adj[arow1 + (size_t)r*GN + co];
  };

  uint64_t mk0, mk1;
  auto adj_pack = [&](int (&p0)[16], int (&p1)[16]){
    uint64_t n0 = 0, n1 = 0;
    #pragma unroll
    for(int r=0;r<16;r++){
      uint64_t b = __ballot(p0[r] != 0);
      if((lane&15)==r) n0 = b;
    }
    #pragma unroll
    for(int r=0;r<16;r++){
      uint64_t b = __ballot(p1[r] != 0);
      if((lane&15)==r) n1 = b;
    }
    mk0 = n0; mk1 = n1;
  };

  auto mkpa = [&](float wh1, unsigned m8, float4 w0, float4 w1) -> bf16x8 {
    bf16x8 pa;
    float y, p;
    y = wh1 + w0.x; y = fmaxf(y, 0.2f*y); p = exp2f(y); pa[0] = (__bf16)((m8    )&1 ? p : 0.f);
    y = wh1 + w0.y; y = fmaxf(y, 0.2f*y); p = exp2f(y); pa[1] = (__bf16)((m8>>1)&1 ? p : 0.f);
    y = wh1 + w0.z; y = fmaxf(y, 0.2f*y); p = exp2f(y); pa[2] = (__bf16)((m8>>2)&1 ? p : 0.f);
    y = wh1 + w0.w; y = fmaxf(y, 0.2f*y); p = exp2f(y); pa[3] = (__bf16)((m8>>3)&1 ? p : 0.f);
    y = wh1 + w1.x; y = fmaxf(y, 0.2f*y); p = exp2f(y); pa[4] = (__bf16)((m8>>4)&1 ? p : 0.f);
    y = wh1 + w1.y; y = fmaxf(y, 0.2f*y); p = exp2f(y); pa[5] = (__bf16)((m8>>5)&1 ? p : 0.f);
    y = wh1 + w1.z; y = fmaxf(y, 0.2f*y); p = exp2f(y); pa[6] = (__bf16)((m8>>6)&1 ? p : 0.f);
    y = wh1 + w1.w; y = fmaxf(y, 0.2f*y); p = exp2f(y); pa[7] = (__bf16)((m8>>7)&1 ? p : 0.f);
    return pa;
  };

  auto kstep = [&](int it, int kk, int buf){
    const float* wp = wh2p + it*64 + kk*32;
    float4 w0 = *(const float4*)wp;
    float4 w1 = *(const float4*)(wp + 4);
    unsigned m8_0 = (unsigned)((mk0 >> (kk*32 + kg8)) & 0xffULL);
    unsigned m8_1 = (unsigned)((mk1 >> (kk*32 + kg8)) & 0xffULL);
    bf16x8 pa0 = mkpa(wh1_0, m8_0, w0, w1);
    bf16x8 pa1 = mkpa(wh1_1, m8_1, w0, w1);
    const int ko = kk*64 + kg*16;
    #pragma unroll
    for(int t=0;t<16;t++){
      int n = 16*t + (lane&15);
      bf16x8 bv = *(const bf16x8*)((const char*)&Vs[buf][0] + n*128 + (ko ^ ((n&7)<<4)));
      acc0[t] = __builtin_amdgcn_mfma_f32_16x16x32_bf16(pa0, bv, acc0[t], 0, 0, 0);
      acc1[t] = __builtin_amdgcn_mfma_f32_16x16x32_bf16(pa1, bv, acc1[t], 0, 0, 0);
    }
    accs0 = __builtin_amdgcn_mfma_f32_16x16x32_bf16(pa0, ones, accs0, 0, 0, 0);
    accs1 = __builtin_amdgcn_mfma_f32_16x16x32_bf16(pa1, ones, accs1, 0, 0, 0);
  };

  auto half = [&](int h, int (&p0)[16], int (&p1)[16]){
    if(h < 15) stage(h+1, (h+1)&1);   // V loads first: oldest after leftover adj(h+1)
    adj_pack(p0, p1);                  // set h&1: loads retired at bottom of h-1 -> no wait
    if(h < 14) adj_load(h+2, p0, p1);  // refill consumed set, 2 halves ahead
    kstep(h, 0, h&1);
    kstep(h, 1, h&1);
    if(h < 15){
      if(h == 14){ asm volatile("s_waitcnt vmcnt(0)"  ::: "memory"); }  // stage(15) certain
      else       { asm volatile("s_waitcnt vmcnt(32)" ::: "memory"); }  // retire adj(h+1)+stage(h+1)
      __builtin_amdgcn_s_barrier();
    }
  };

  // prologue: V(0) + adj(0) + adj(1) in flight; retire stage only (issue-cap keeps ~49 adj in flight)
  stage(0, 0);
  adj_load(0, aA0, aA1);
  adj_load(1, aB0, aB1);
  asm volatile("s_waitcnt vmcnt(40)" ::: "memory");
  __builtin_amdgcn_s_barrier();

  for(int hp=0; hp<8; ++hp){
    half(2*hp,   aA0, aA1);
    half(2*hp+1, aB0, aB1);
  }

  const int orow0 = r0 + 16*w + 4*kg;
  const int orow1 = orow0 + 64;
  const int ocol  = lane & 15;
  if constexpr (PART){
    float* pv = pv_out + (size_t)chunk*GN*GOUT;
    float* sp = s_out  + (size_t)chunk*GN;
    #pragma unroll
    for(int t=0;t<16;t++){
      #pragma unroll
      for(int r=0;r<4;r++){
        pv[(size_t)(orow0 + r)*GOUT + ocol + 16*t] = acc0[t][r];
        pv[(size_t)(orow1 + r)*GOUT + ocol + 16*t] = acc1[t][r];
      }
    }
    if(ocol == 0){
      #pragma unroll
      for(int r=0;r<4;r++){ sp[orow0 + r] = accs0[r]; sp[orow1 + r] = accs1[r]; }
    }
  } else {
    #pragma unroll
    for(int t=0;t<16;t++){
      #pragma unroll
      for(int r=0;r<4;r++){
        atomicAdd(pv_out + (size_t)(orow0 + r)*GOUT + ocol + 16*t, acc0[t][r]);
        atomicAdd(pv_out + (size_t)(orow1 + r)*GOUT + ocol + 16*t, acc1[t][r]);
      }
    }
    if(ocol == 0){
      #pragma unroll
      for(int r=0;r<4;r++){ atomicAdd(s_out + orow0 + r, accs0[r]); atomicAdd(s_out + orow1 + r, accs1[r]); }
    }
  }
}

// ---------------- epilogues ----------------
static __device__ __forceinline__ float elu1(float x){
  return x > 0.f ? x : (exp2f(x*LOG2E) - 1.f);
}

// PART path: combine 8 partials + normalize + ELU
__global__ void k_reduce(const float* __restrict__ accP, const float* __restrict__ accSp,
                         float* __restrict__ out){
  size_t i = ((size_t)blockIdx.x*256 + threadIdx.x)*4;
  int row = (int)(i >> 8);
  float S = 0.f;
  #pragma unroll
  for(int c=0;c<8;c++) S += accSp[(size_t)c*GN + row];
  float4 s = {0.f,0.f,0.f,0.f};
  #pragma unroll
  for(int c=0;c<8;c++){
    float4 v = *(const float4*)(accP + (size_t)c*GN*GOUT + i);
    s.x += v.x; s.y += v.y; s.z += v.z; s.w += v.w;
  }
  float inv = 1.0f / S;
  float4 o;
  o.x = elu1(s.x*inv); o.y = elu1(s.y*inv); o.z = elu1(s.z*inv); o.w = elu1(s.w*inv);
  *(float4*)(out + i) = o;
}

// atomic path: normalize + ELU
__global__ void k_norm(const float* __restrict__ accPV, const float* __restrict__ accS,
                       float* __restrict__ out){
  size_t i = ((size_t)blockIdx.x*256 + threadIdx.x)*4;
  int row = (int)(i >> 8);
  float inv = 1.0f / accS[row];
  float4 v = *(const float4*)(accPV + i);
  float4 o;
  o.x = elu1(v.x*inv); o.y = elu1(v.y*inv); o.z = elu1(v.z*inv); o.w = elu1(v.w*inv);
  *(float4*)(out + i) = o;
}

// ---------------- launch ----------------
extern "C" void kernel_launch(void* const* d_in, const int* in_sizes, int n_in,
                              void* d_out, int out_size, void* d_ws, size_t ws_size,
                              hipStream_t stream){
  const float* h  = (const float*)d_in[0];
  const int*   adj= (const int*)  d_in[1];
  const float* W  = (const float*)d_in[2];
  const float* al = (const float*)d_in[3];
  const float* ar = (const float*)d_in[4];
  float* out = (float*)d_out;
  char* ws = (char*)d_ws;

  const size_t SZ_ACCP = (size_t)8*GN*GOUT*4;        // 67,108,864
  const size_t NEED_A  = SZ_ACCP + 4194304 + 32768 + 32768 + 262144; // 71,630,848

  if(ws_size >= NEED_A){
    float*  accP  = (float*) (ws);
    __bf16* hb    = (__bf16*)(ws);                       // alias (prep-only)
    __bf16* WT    = (__bf16*)(ws + 8388608);             // alias (prep-only)
    float*  wal   = (float*) (ws + 8650752);             // alias (prep-only)
    float*  war   = (float*) (ws + 8652800);             // alias (prep-only)
    __bf16* WhbT  = (__bf16*)(ws + SZ_ACCP);
    float*  Wh1   = (float*) (ws + SZ_ACCP + 4194304);
    float*  Wh2   = (float*) (ws + SZ_ACCP + 4227072);
    float*  accSp = (float*) (ws + SZ_ACCP + 4259840);

    k_wprep <<<512, 64, 0, stream>>>(W, al, ar, wal, war, WT);
    k_prep_h<<<2048, 256, 0, stream>>>(h, wal, war, hb, Wh1, Wh2);
    k_gemmT <<<256, 256, 0, stream>>>(WT, hb, WhbT);
    k_attn<true><<<512, 256, 0, stream>>>(adj, WhbT, Wh1, Wh2, accP, accSp);
    k_reduce<<<2048, 256, 0, stream>>>(accP, accSp, out);
  } else {
    float*  accPV = (float*) (ws);                       //  8,388,608
    float*  accS  = (float*) (ws + 8388608);             //     32,768
    __bf16* hb    = (__bf16*)(ws + 8421376);             //  8,388,608
    __bf16* WT    = (__bf16*)(ws + 16809984);            //    262,144
    __bf16* WhbT  = (__bf16*)(ws + 17072128);            //  4,194,304
    float*  wal   = (float*) (ws + 21266432);
    float*  war   = (float*) (ws + 21268480);
    float*  Wh1   = (float*) (ws + 21270528);
    float*  Wh2   = (float*) (ws + 21303296);
    if(ws_size < 21336064) return;

    hipMemsetAsync(accPV, 0, 8388608 + 32768, stream);
    k_wprep <<<512, 64, 0, stream>>>(W, al, ar, wal, war, WT);
    k_prep_h<<<2048, 256, 0, stream>>>(h, wal, war, hb, Wh1, Wh2);
    k_gemmT <<<256, 256, 0, stream>>>(WT, hb, WhbT);
    k_attn<false><<<512, 256, 0, stream>>>(adj, WhbT, Wh1, Wh2, accPV, accS);
    k_norm  <<<2048, 256, 0, stream>>>(accPV, accS, out);
  }
}

// Round 8
// 153.456 us; speedup vs baseline: 12.2325x; 12.2325x over previous
//
#include <hip/hip_runtime.h>
#include <hip/hip_bf16.h>
#include <cstdint>
#include <cstddef>

typedef float  f32x4  __attribute__((ext_vector_type(4)));
typedef __bf16 bf16x8 __attribute__((ext_vector_type(8)));

#define LOG2E 1.4426950408889634f

static constexpr int GN   = 8192;   // nodes
static constexpr int GIN  = 512;    // in features
static constexpr int GOUT = 256;    // out features

// ---------------- async global->LDS (width 16) ----------------
static __device__ __forceinline__ void gload_lds16(const void* g, void* lds){
  typedef uint32_t __attribute__((address_space(1)))* gp_t;
  typedef uint32_t __attribute__((address_space(3)))* lp_t;
  __builtin_amdgcn_global_load_lds((gp_t)(uintptr_t)g,
                                   (lp_t)(uint32_t)(uintptr_t)lds, 16, 0, 0);
}

// ---------------- adj -> packed bitmask: pk[j32][row], bit b = adj[row][j32*32+b] ----
// 2048 blocks x 256 thr. Wave W: j-block jb=W&127 (64 j), row-hexadecet loop.
// Per iter: 16 coalesced 256B loads -> 16 ballots -> cndmask tree -> 32 lanes store u32.
__global__ __launch_bounds__(256) void k_pack(const int* __restrict__ adj,
                                              unsigned int* __restrict__ pk){
  const int lane = threadIdx.x & 63;
  const int W = blockIdx.x*4 + (threadIdx.x>>6);
  const int jb = W & 127;
  const int g  = W >> 7;
  const size_t cb = (size_t)jb*64 + lane;
  const int idx = lane & 15;
  #pragma unroll 1
  for(int i=0;i<8;i++){
    const int r0 = (g*8 + i)*16;
    int a[16];
    #pragma unroll
    for(int r=0;r<16;r++) a[r] = adj[(size_t)(r0+r)*GN + cb];
    uint64_t b0 = __ballot(a[0]!=0),  b1 = __ballot(a[1]!=0);
    uint64_t b2 = __ballot(a[2]!=0),  b3 = __ballot(a[3]!=0);
    uint64_t b4 = __ballot(a[4]!=0),  b5 = __ballot(a[5]!=0);
    uint64_t b6 = __ballot(a[6]!=0),  b7 = __ballot(a[7]!=0);
    uint64_t b8 = __ballot(a[8]!=0),  b9 = __ballot(a[9]!=0);
    uint64_t bA = __ballot(a[10]!=0), bB = __ballot(a[11]!=0);
    uint64_t bC = __ballot(a[12]!=0), bD = __ballot(a[13]!=0);
    uint64_t bE = __ballot(a[14]!=0), bF = __ballot(a[15]!=0);
    // select b[idx] via explicit tree (no runtime indexing -> no scratch)
    uint64_t c0 = (idx&1)? b1:b0, c1 = (idx&1)? b3:b2;
    uint64_t c2 = (idx&1)? b5:b4, c3 = (idx&1)? b7:b6;
    uint64_t c4 = (idx&1)? b9:b8, c5 = (idx&1)? bB:bA;
    uint64_t c6 = (idx&1)? bD:bC, c7 = (idx&1)? bF:bE;
    uint64_t d0 = (idx&2)? c1:c0, d1 = (idx&2)? c3:c2;
    uint64_t d2 = (idx&2)? c5:c4, d3 = (idx&2)? c7:c6;
    uint64_t e0 = (idx&4)? d1:d0, e1 = (idx&4)? d3:d2;
    uint64_t v  = (idx&8)? e1:e0;
    unsigned int hword = (lane&16)? (unsigned int)(v>>32) : (unsigned int)v;
    if(lane < 32){
      pk[(size_t)(2*jb + (lane>>4))*GN + r0 + idx] = hword;
    }
  }
}

// ---------------- prep kernels ----------------
// wal/war = (W @ a_{l,r}) * log2(e)  AND  WT[c][k] = bf16(W[k][c]). 512 blocks x 64.
__global__ void k_wprep(const float* __restrict__ W, const float* __restrict__ al,
                        const float* __restrict__ ar, float* __restrict__ wal,
                        float* __restrict__ war, __bf16* __restrict__ WT){
  int k = blockIdx.x;
  int lane = threadIdx.x;
  float4 wv = ((const float4*)(W + (size_t)k*GOUT))[lane];
  float4 av = ((const float4*)al)[lane];
  float4 bv = ((const float4*)ar)[lane];
  WT[(size_t)(lane*4+0)*GIN + k] = (__bf16)wv.x;
  WT[(size_t)(lane*4+1)*GIN + k] = (__bf16)wv.y;
  WT[(size_t)(lane*4+2)*GIN + k] = (__bf16)wv.z;
  WT[(size_t)(lane*4+3)*GIN + k] = (__bf16)wv.w;
  float sl = wv.x*av.x + wv.y*av.y + wv.z*av.z + wv.w*av.w;
  float sr = wv.x*bv.x + wv.y*bv.y + wv.z*bv.z + wv.w*bv.w;
  #pragma unroll
  for(int o=32;o;o>>=1){ sl += __shfl_down(sl,o,64); sr += __shfl_down(sr,o,64); }
  if(lane==0){ wal[k] = sl*LOG2E; war[k] = sr*LOG2E; }
}

// fused: hb = bf16(h); Wh1/Wh2 fp32 row-dots. 4 rows/block.
__global__ void k_prep_h(const float* __restrict__ h, const float* __restrict__ wal,
                         const float* __restrict__ war, __bf16* __restrict__ hb,
                         float* __restrict__ Wh1, float* __restrict__ Wh2){
  int row = blockIdx.x*4 + (threadIdx.x>>6);
  int lane = threadIdx.x & 63;
  const float4* hp = (const float4*)(h + (size_t)row*GIN);
  float4 v0 = hp[lane*2], v1 = hp[lane*2+1];
  bf16x8 o;
  o[0]=(__bf16)v0.x; o[1]=(__bf16)v0.y; o[2]=(__bf16)v0.z; o[3]=(__bf16)v0.w;
  o[4]=(__bf16)v1.x; o[5]=(__bf16)v1.y; o[6]=(__bf16)v1.z; o[7]=(__bf16)v1.w;
  *(bf16x8*)(hb + (size_t)row*GIN + lane*8) = o;
  float4 a0 = ((const float4*)wal)[lane*2], a1 = ((const float4*)wal)[lane*2+1];
  float4 b0 = ((const float4*)war)[lane*2], b1 = ((const float4*)war)[lane*2+1];
  float sl = v0.x*a0.x+v0.y*a0.y+v0.z*a0.z+v0.w*a0.w
           + v1.x*a1.x+v1.y*a1.y+v1.z*a1.z+v1.w*a1.w;
  float sr = v0.x*b0.x+v0.y*b0.y+v0.z*b0.z+v0.w*b0.w
           + v1.x*b1.x+v1.y*b1.y+v1.z*b1.z+v1.w*b1.w;
  #pragma unroll
  for(int of=32;of;of>>=1){ sl += __shfl_down(sl,of,64); sr += __shfl_down(sr,of,64); }
  if(lane==0){ Wh1[row]=sl; Wh2[row]=sr; }
}

// ---------------- GEMM: WhbT[m][n] = sum_k WT[m][k]*hb[n][k]  (= (h@W)^T, bf16)
__global__ __launch_bounds__(256,1) void k_gemmT(const __bf16* __restrict__ WT,
                                                 const __bf16* __restrict__ hb,
                                                 __bf16* __restrict__ WhbT){
  __shared__ __attribute__((aligned(16))) __bf16 As[2][64*64];
  __shared__ __attribute__((aligned(16))) __bf16 Bs[2][128*64];
  const int tid = threadIdx.x, lane = tid & 63, w = tid >> 6;
  const int mb = blockIdx.x >> 6, nb = blockIdx.x & 63;
  const int m0 = mb*64, n0 = nb*128;

  f32x4 acc[8];
  #pragma unroll
  for(int t=0;t<8;t++) acc[t] = (f32x4){0.f,0.f,0.f,0.f};

  const int lr = lane>>3;
  const int bs_sw = ((lane&7)*16) ^ (lr<<4);

  auto stage = [&](int it, int buf){
    const int k0b = it*128;
    #pragma unroll
    for(int s=0;s<6;s++){
      int u = w + s*4;
      const char* src; char* dst;
      if(u < 8){
        int r8 = u*8;
        src = (const char*)(WT + (size_t)(m0 + r8 + lr)*GIN);
        dst = (char*)&As[buf][0] + r8*128;
      } else {
        int r8 = (u-8)*8;
        src = (const char*)(hb + (size_t)(n0 + r8 + lr)*GIN);
        dst = (char*)&Bs[buf][0] + r8*128;
      }
      gload_lds16(src + k0b + bs_sw, dst);
    }
  };

  auto kstep = [&](int kk, int buf){
    const int ko = kk*64 + (lane>>4)*16;
    const int am = 16*w + (lane&15);
    bf16x8 af = *(const bf16x8*)((const char*)&As[buf][0] + am*128 + (ko ^ ((am&7)<<4)));
    #pragma unroll
    for(int t=0;t<8;t++){
      int n = 16*t + (lane&15);
      bf16x8 bf = *(const bf16x8*)((const char*)&Bs[buf][0] + n*128 + (ko ^ ((n&7)<<4)));
      acc[t] = __builtin_amdgcn_mfma_f32_16x16x32_bf16(af, bf, acc[t], 0, 0, 0);
    }
  };

  stage(0,0);
  asm volatile("s_waitcnt vmcnt(0)" ::: "memory");
  __builtin_amdgcn_s_barrier();
  for(int it=0; it<8; it++){
    int buf = it & 1;
    if(it < 7) stage(it+1, buf^1);
    kstep(0, buf);
    kstep(1, buf);
    asm volatile("s_waitcnt vmcnt(0)" ::: "memory");
    __builtin_amdgcn_s_barrier();
  }

  const int mrow = m0 + 16*w + 4*(lane>>4);
  const int nc0  = n0 + (lane&15);
  #pragma unroll
  for(int t=0;t<8;t++){
    #pragma unroll
    for(int r=0;r<4;r++){
      WhbT[(size_t)(mrow + r)*GN + nc0 + 16*t] = (__bf16)acc[t][r];
    }
  }
}

// ---------------- fused masked-softmax-attention (mask-from-LDS, zero HBM in loop) --
// grid 512: rg=bid>>3 (64 rowgroups of 128), chunk=bid&7 (1024 cols)
// block 256 thr / 4 waves; wave owns rows +0..15 and +64..79 (2 MFMA sets).
// Masks pre-packed by k_pack, staged once to LDS (16KB). V staged 32 j-cols/iter
// into pair-row XOR layout: phys (pairrow r, slot s) holds logical l = s^(r&7),
// l = (odd<<2)|kg -> outcol 2r+odd, j-bytes kg*16..+15. Same slot-occupancy as the
// r4 swizzle that measured 0 bank conflicts.
template<bool PART>
__global__ __launch_bounds__(256,2) void k_attn(const unsigned int* __restrict__ pk,
                                                const __bf16* __restrict__ WhbT,
                                                const float* __restrict__ Wh1s,
                                                const float* __restrict__ Wh2s,
                                                float* __restrict__ pv_out,
                                                float* __restrict__ s_out){
  __shared__ __attribute__((aligned(16))) char Vs[2][16384];
  __shared__ unsigned int mkL[32*128];
  const int tid = threadIdx.x, lane = tid & 63, w = tid >> 6;
  const int rg = blockIdx.x >> 3, chunk = blockIdx.x & 7;
  const int r0 = rg * 128;
  const int j0 = chunk * 1024;
  const int la = lane & 15, kg = lane >> 4, kg8 = kg << 3;

  f32x4 acc0[16], acc1[16];
  #pragma unroll
  for(int t=0;t<16;t++){ acc0[t] = (f32x4){0.f,0.f,0.f,0.f}; acc1[t] = (f32x4){0.f,0.f,0.f,0.f}; }
  f32x4 accs0 = (f32x4){0.f,0.f,0.f,0.f};
  f32x4 accs1 = (f32x4){0.f,0.f,0.f,0.f};

  bf16x8 ones;
  #pragma unroll
  for(int j=0;j<8;j++) ones[j] = (__bf16)1.0f;

  const int myrow0 = r0 + 16*w + la;
  const float wh1_0 = Wh1s[myrow0];                 // pre-scaled by log2(e)
  const float wh1_1 = Wh1s[myrow0 + 64];

  // ---- stage packed masks: mkL[j32l*128 + row] ----
  {
    const unsigned int* src = pk + (size_t)(chunk*32)*GN + r0;
    #pragma unroll
    for(int s=0;s<16;s++){
      int idx = s*256 + tid;
      mkL[idx] = src[(size_t)(idx>>7)*GN + (idx&127)];
    }
  }

  // ---- V stage per-lane constants (lane-only; see header comment) ----
  const int l_log = (lane&7) ^ (lane>>3);
  const char* wbase = (const char*)WhbT
                    + (size_t)(64*w + 2*(lane>>3) + (l_log>>2))*(GN*2)
                    + (size_t)(l_log&3)*16;
  char* dbase_flag = nullptr; (void)dbase_flag;

  auto stage = [&](int it, int buf){
    const size_t colb = (size_t)(j0 + it*32)*2;
    char* dst = &Vs[buf][0] + w*4096 + lane*16;
    #pragma unroll
    for(int s=0;s<4;s++){
      gload_lds16(wbase + (size_t)(16*s)*(GN*2) + colb, dst + s*1024);
    }
  };

  auto mkpa = [&](float wh1, unsigned m8, float4 w0, float4 w1) -> bf16x8 {
    bf16x8 pa;
    float y, p;
    y = wh1 + w0.x; y = fmaxf(y, 0.2f*y); p = exp2f(y); pa[0] = (__bf16)((m8    )&1 ? p : 0.f);
    y = wh1 + w0.y; y = fmaxf(y, 0.2f*y); p = exp2f(y); pa[1] = (__bf16)((m8>>1)&1 ? p : 0.f);
    y = wh1 + w0.z; y = fmaxf(y, 0.2f*y); p = exp2f(y); pa[2] = (__bf16)((m8>>2)&1 ? p : 0.f);
    y = wh1 + w0.w; y = fmaxf(y, 0.2f*y); p = exp2f(y); pa[3] = (__bf16)((m8>>3)&1 ? p : 0.f);
    y = wh1 + w1.x; y = fmaxf(y, 0.2f*y); p = exp2f(y); pa[4] = (__bf16)((m8>>4)&1 ? p : 0.f);
    y = wh1 + w1.y; y = fmaxf(y, 0.2f*y); p = exp2f(y); pa[5] = (__bf16)((m8>>5)&1 ? p : 0.f);
    y = wh1 + w1.z; y = fmaxf(y, 0.2f*y); p = exp2f(y); pa[6] = (__bf16)((m8>>6)&1 ? p : 0.f);
    y = wh1 + w1.w; y = fmaxf(y, 0.2f*y); p = exp2f(y); pa[7] = (__bf16)((m8>>7)&1 ? p : 0.f);
    return pa;
  };

  // per-lane read base into V tile (pair-row + XOR slot), +t*1024 folds to immediate
  const int rd_off = (la>>1)*128 + (((((la&1)<<2) | kg) ^ (la>>1)) << 4);

  auto kstep = [&](int it, int buf){
    unsigned int m32_0 = mkL[it*128 + 16*w + la];
    unsigned int m32_1 = mkL[it*128 + 16*w + la + 64];
    const float* wp = Wh2s + j0 + it*32 + kg8;
    float4 w0 = *(const float4*)wp;
    float4 w1 = *(const float4*)(wp + 4);
    bf16x8 pa0 = mkpa(wh1_0, (m32_0 >> kg8) & 0xffu, w0, w1);
    bf16x8 pa1 = mkpa(wh1_1, (m32_1 >> kg8) & 0xffu, w0, w1);
    const char* vb = &Vs[buf][0] + rd_off;
    #pragma unroll
    for(int t=0;t<16;t++){
      bf16x8 bv = *(const bf16x8*)(vb + t*1024);
      acc0[t] = __builtin_amdgcn_mfma_f32_16x16x32_bf16(pa0, bv, acc0[t], 0, 0, 0);
      acc1[t] = __builtin_amdgcn_mfma_f32_16x16x32_bf16(pa1, bv, acc1[t], 0, 0, 0);
    }
    accs0 = __builtin_amdgcn_mfma_f32_16x16x32_bf16(pa0, ones, accs0, 0, 0, 0);
    accs1 = __builtin_amdgcn_mfma_f32_16x16x32_bf16(pa1, ones, accs1, 0, 0, 0);
  };

  stage(0, 0);
  __syncthreads();                    // drains gload_lds (vmcnt) + mask ds_writes (lgkm)

  for(int it=0; it<32; it++){
    int buf = it & 1;
    if(it < 31) stage(it+1, buf^1);   // L2-hit loads hide under kstep
    kstep(it, buf);
    asm volatile("s_waitcnt vmcnt(0)" ::: "memory");
    __builtin_amdgcn_s_barrier();
  }

  const int orow0 = r0 + 16*w + 4*kg;
  const int orow1 = orow0 + 64;
  const int ocol  = la;
  if constexpr (PART){
    float* pv = pv_out + (size_t)chunk*GN*GOUT;
    float* sp = s_out  + (size_t)chunk*GN;
    #pragma unroll
    for(int t=0;t<16;t++){
      #pragma unroll
      for(int r=0;r<4;r++){
        pv[(size_t)(orow0 + r)*GOUT + ocol + 16*t] = acc0[t][r];
        pv[(size_t)(orow1 + r)*GOUT + ocol + 16*t] = acc1[t][r];
      }
    }
    if(ocol == 0){
      #pragma unroll
      for(int r=0;r<4;r++){ sp[orow0 + r] = accs0[r]; sp[orow1 + r] = accs1[r]; }
    }
  } else {
    #pragma unroll
    for(int t=0;t<16;t++){
      #pragma unroll
      for(int r=0;r<4;r++){
        atomicAdd(pv_out + (size_t)(orow0 + r)*GOUT + ocol + 16*t, acc0[t][r]);
        atomicAdd(pv_out + (size_t)(orow1 + r)*GOUT + ocol + 16*t, acc1[t][r]);
      }
    }
    if(ocol == 0){
      #pragma unroll
      for(int r=0;r<4;r++){ atomicAdd(s_out + orow0 + r, accs0[r]); atomicAdd(s_out + orow1 + r, accs1[r]); }
    }
  }
}

// ---------------- epilogues ----------------
static __device__ __forceinline__ float elu1(float x){
  return x > 0.f ? x : (exp2f(x*LOG2E) - 1.f);
}

// PART path: combine 8 partials + normalize + ELU
__global__ void k_reduce(const float* __restrict__ accP, const float* __restrict__ accSp,
                         float* __restrict__ out){
  size_t i = ((size_t)blockIdx.x*256 + threadIdx.x)*4;
  int row = (int)(i >> 8);
  float S = 0.f;
  #pragma unroll
  for(int c=0;c<8;c++) S += accSp[(size_t)c*GN + row];
  float4 s = {0.f,0.f,0.f,0.f};
  #pragma unroll
  for(int c=0;c<8;c++){
    float4 v = *(const float4*)(accP + (size_t)c*GN*GOUT + i);
    s.x += v.x; s.y += v.y; s.z += v.z; s.w += v.w;
  }
  float inv = 1.0f / S;
  float4 o;
  o.x = elu1(s.x*inv); o.y = elu1(s.y*inv); o.z = elu1(s.z*inv); o.w = elu1(s.w*inv);
  *(float4*)(out + i) = o;
}

// atomic path: normalize + ELU
__global__ void k_norm(const float* __restrict__ accPV, const float* __restrict__ accS,
                       float* __restrict__ out){
  size_t i = ((size_t)blockIdx.x*256 + threadIdx.x)*4;
  int row = (int)(i >> 8);
  float inv = 1.0f / accS[row];
  float4 v = *(const float4*)(accPV + i);
  float4 o;
  o.x = elu1(v.x*inv); o.y = elu1(v.y*inv); o.z = elu1(v.z*inv); o.w = elu1(v.w*inv);
  *(float4*)(out + i) = o;
}

// ---------------- launch ----------------
extern "C" void kernel_launch(void* const* d_in, const int* in_sizes, int n_in,
                              void* d_out, int out_size, void* d_ws, size_t ws_size,
                              hipStream_t stream){
  const float* h  = (const float*)d_in[0];
  const int*   adj= (const int*)  d_in[1];
  const float* W  = (const float*)d_in[2];
  const float* al = (const float*)d_in[3];
  const float* ar = (const float*)d_in[4];
  float* out = (float*)d_out;
  char* ws = (char*)d_ws;

  const size_t SZ_ACCP = (size_t)8*GN*GOUT*4;        // 67,108,864
  const size_t SZ_PK   = (size_t)256*GN*4;           //  8,388,608
  const size_t NEED_A  = SZ_ACCP + 4194304 + 32768 + 32768 + 262144 + SZ_PK;

  if(ws_size >= NEED_A){
    float*  accP  = (float*) (ws);
    __bf16* hb    = (__bf16*)(ws);                       // alias (prep-only)
    __bf16* WT    = (__bf16*)(ws + 8388608);             // alias (prep-only)
    float*  wal   = (float*) (ws + 8650752);             // alias (prep-only)
    float*  war   = (float*) (ws + 8652800);             // alias (prep-only)
    __bf16* WhbT  = (__bf16*)(ws + SZ_ACCP);
    float*  Wh1   = (float*) (ws + SZ_ACCP + 4194304);
    float*  Wh2   = (float*) (ws + SZ_ACCP + 4227072);
    float*  accSp = (float*) (ws + SZ_ACCP + 4259840);
    unsigned int* pk = (unsigned int*)(ws + SZ_ACCP + 4521984);

    k_wprep <<<512, 64, 0, stream>>>(W, al, ar, wal, war, WT);
    k_prep_h<<<2048, 256, 0, stream>>>(h, wal, war, hb, Wh1, Wh2);
    k_gemmT <<<256, 256, 0, stream>>>(WT, hb, WhbT);
    k_pack  <<<2048, 256, 0, stream>>>(adj, pk);
    k_attn<true><<<512, 256, 0, stream>>>(pk, WhbT, Wh1, Wh2, accP, accSp);
    k_reduce<<<2048, 256, 0, stream>>>(accP, accSp, out);
  } else {
    float*  accPV = (float*) (ws);                       //  8,388,608
    float*  accS  = (float*) (ws + 8388608);             //     32,768
    __bf16* hb    = (__bf16*)(ws + 8421376);             //  8,388,608
    __bf16* WT    = (__bf16*)(ws + 16809984);            //    262,144
    __bf16* WhbT  = (__bf16*)(ws + 17072128);            //  4,194,304
    float*  wal   = (float*) (ws + 21266432);
    float*  war   = (float*) (ws + 21268480);
    float*  Wh1   = (float*) (ws + 21270528);
    float*  Wh2   = (float*) (ws + 21303296);
    unsigned int* pk = (unsigned int*)(ws + 21336064);
    if(ws_size < 21336064 + SZ_PK) return;

    hipMemsetAsync(accPV, 0, 8388608 + 32768, stream);
    k_wprep <<<512, 64, 0, stream>>>(W, al, ar, wal, war, WT);
    k_prep_h<<<2048, 256, 0, stream>>>(h, wal, war, hb, Wh1, Wh2);
    k_gemmT <<<256, 256, 0, stream>>>(WT, hb, WhbT);
    k_pack  <<<2048, 256, 0, stream>>>(adj, pk);
    k_attn<false><<<512, 256, 0, stream>>>(pk, WhbT, Wh1, Wh2, accPV, accS);
    k_norm  <<<2048, 256, 0, stream>>>(accPV, accS, out);
  }
}

// Round 9
// 144.644 us; speedup vs baseline: 12.9777x; 1.0609x over previous
//
#include <hip/hip_runtime.h>
#include <hip/hip_bf16.h>
#include <cstdint>
#include <cstddef>

typedef float  f32x4  __attribute__((ext_vector_type(4)));
typedef __bf16 bf16x8 __attribute__((ext_vector_type(8)));

#define LOG2E 1.4426950408889634f

static constexpr int GN   = 8192;   // nodes
static constexpr int GIN  = 512;    // in features
static constexpr int GOUT = 256;    // out features

// ---------------- async global->LDS (width 16) ----------------
static __device__ __forceinline__ void gload_lds16(const void* g, void* lds){
  typedef uint32_t __attribute__((address_space(1)))* gp_t;
  typedef uint32_t __attribute__((address_space(3)))* lp_t;
  __builtin_amdgcn_global_load_lds((gp_t)(uintptr_t)g,
                                   (lp_t)(uint32_t)(uintptr_t)lds, 16, 0, 0);
}

// ================= L1: [wal/war: 128 blk][W-transpose: 32 blk][h->bf16: 2048 blk] ====
__global__ __launch_bounds__(256) void k_pre1(const float* __restrict__ W,
                                              const float* __restrict__ al,
                                              const float* __restrict__ ar,
                                              const float* __restrict__ h,
                                              float* __restrict__ wal,
                                              float* __restrict__ war,
                                              __bf16* __restrict__ WT,
                                              __bf16* __restrict__ hb){
  __shared__ float T[64][65];
  const int bid = blockIdx.x, tid = threadIdx.x;
  if(bid < 128){
    // wal/war = (W @ a_{l,r}) * log2(e); one warp per k
    const int k = bid*4 + (tid>>6), lane = tid & 63;
    float4 wv = ((const float4*)(W + (size_t)k*GOUT))[lane];
    float4 av = ((const float4*)al)[lane];
    float4 bv = ((const float4*)ar)[lane];
    float sl = wv.x*av.x + wv.y*av.y + wv.z*av.z + wv.w*av.w;
    float sr = wv.x*bv.x + wv.y*bv.y + wv.z*bv.z + wv.w*bv.w;
    #pragma unroll
    for(int o=32;o;o>>=1){ sl += __shfl_down(sl,o,64); sr += __shfl_down(sr,o,64); }
    if(lane==0){ wal[k] = sl*LOG2E; war[k] = sr*LOG2E; }
  } else if(bid < 160){
    // WT[c][k] = bf16(W[k][c]) via LDS tile (coalesced both sides)
    const int tile = bid - 128;
    const int k0 = (tile>>2)*64, c0 = (tile&3)*64;
    const int r = tid>>2, cs = (tid&3)*16;
    #pragma unroll
    for(int j=0;j<4;j++){
      float4 v = *(const float4*)(W + (size_t)(k0+r)*GOUT + c0 + cs + 4*j);
      T[r][cs+4*j+0]=v.x; T[r][cs+4*j+1]=v.y; T[r][cs+4*j+2]=v.z; T[r][cs+4*j+3]=v.w;
    }
    __syncthreads();
    bf16x8 o1, o2;
    #pragma unroll
    for(int j=0;j<8;j++){ o1[j]=(__bf16)T[cs+j][r]; o2[j]=(__bf16)T[cs+8+j][r]; }
    __bf16* dst = WT + (size_t)(c0+r)*GIN + k0 + cs;
    *(bf16x8*)dst = o1;
    *(bf16x8*)(dst+8) = o2;
  } else {
    // hb = bf16(h)
    size_t i = ((size_t)(bid-160)*256 + tid)*8;
    float4 v0 = *(const float4*)(h+i);
    float4 v1 = *(const float4*)(h+i+4);
    bf16x8 o;
    o[0]=(__bf16)v0.x; o[1]=(__bf16)v0.y; o[2]=(__bf16)v0.z; o[3]=(__bf16)v0.w;
    o[4]=(__bf16)v1.x; o[5]=(__bf16)v1.y; o[6]=(__bf16)v1.z; o[7]=(__bf16)v1.w;
    *(bf16x8*)(hb+i) = o;
  }
}

// ================= L2 mega: [pack: 2048][gemmT: 256][Wh12: 2048] — independent roles
__global__ __launch_bounds__(256) void k_pre2(const int* __restrict__ adj,
                                              unsigned int* __restrict__ pk,
                                              const __bf16* __restrict__ WT,
                                              const __bf16* __restrict__ hb,
                                              __bf16* __restrict__ WhbT,
                                              const float* __restrict__ h,
                                              const float* __restrict__ wal,
                                              const float* __restrict__ war,
                                              float* __restrict__ Wh1,
                                              float* __restrict__ Wh2){
  __shared__ __attribute__((aligned(16))) __bf16 As[2][64*64];
  __shared__ __attribute__((aligned(16))) __bf16 Bs[2][128*64];
  const int bid = blockIdx.x, tid = threadIdx.x;
  const int lane = tid & 63, w = tid >> 6;

  if(bid < 2048){
    // ---- pack: adj -> bitmask pk[j32][row] (BW-bound streamer, dispatched first)
    const int Wv = bid*4 + w;
    const int jb = Wv & 127;
    const int g  = Wv >> 7;
    const size_t cb = (size_t)jb*64 + lane;
    const int idx = lane & 15;
    #pragma unroll 1
    for(int i=0;i<8;i++){
      const int r0 = (g*8 + i)*16;
      int a[16];
      #pragma unroll
      for(int r=0;r<16;r++) a[r] = adj[(size_t)(r0+r)*GN + cb];
      uint64_t b0 = __ballot(a[0]!=0),  b1 = __ballot(a[1]!=0);
      uint64_t b2 = __ballot(a[2]!=0),  b3 = __ballot(a[3]!=0);
      uint64_t b4 = __ballot(a[4]!=0),  b5 = __ballot(a[5]!=0);
      uint64_t b6 = __ballot(a[6]!=0),  b7 = __ballot(a[7]!=0);
      uint64_t b8 = __ballot(a[8]!=0),  b9 = __ballot(a[9]!=0);
      uint64_t bA = __ballot(a[10]!=0), bB = __ballot(a[11]!=0);
      uint64_t bC = __ballot(a[12]!=0), bD = __ballot(a[13]!=0);
      uint64_t bE = __ballot(a[14]!=0), bF = __ballot(a[15]!=0);
      uint64_t c0 = (idx&1)? b1:b0, c1 = (idx&1)? b3:b2;
      uint64_t c2 = (idx&1)? b5:b4, c3 = (idx&1)? b7:b6;
      uint64_t c4 = (idx&1)? b9:b8, c5 = (idx&1)? bB:bA;
      uint64_t c6 = (idx&1)? bD:bC, c7 = (idx&1)? bF:bE;
      uint64_t d0 = (idx&2)? c1:c0, d1 = (idx&2)? c3:c2;
      uint64_t d2 = (idx&2)? c5:c4, d3 = (idx&2)? c7:c6;
      uint64_t e0 = (idx&4)? d1:d0, e1 = (idx&4)? d3:d2;
      uint64_t v  = (idx&8)? e1:e0;
      unsigned int hword = (lane&16)? (unsigned int)(v>>32) : (unsigned int)v;
      if(lane < 32){
        pk[(size_t)(2*jb + (lane>>4))*GN + r0 + idx] = hword;
      }
    }
  } else if(bid < 2304){
    // ---- gemmT: WhbT[m][n] = sum_k WT[m][k]*hb[n][k]
    const int b2 = bid - 2048;
    const int mb = b2 >> 6, nb = b2 & 63;
    const int m0 = mb*64, n0 = nb*128;

    f32x4 acc[8];
    #pragma unroll
    for(int t=0;t<8;t++) acc[t] = (f32x4){0.f,0.f,0.f,0.f};

    const int lr = lane>>3;
    const int bs_sw = ((lane&7)*16) ^ (lr<<4);

    auto stage = [&](int it, int buf){
      const int k0b = it*128;
      #pragma unroll
      for(int s=0;s<6;s++){
        int u = w + s*4;
        const char* src; char* dst;
        if(u < 8){
          int r8 = u*8;
          src = (const char*)(WT + (size_t)(m0 + r8 + lr)*GIN);
          dst = (char*)&As[buf][0] + r8*128;
        } else {
          int r8 = (u-8)*8;
          src = (const char*)(hb + (size_t)(n0 + r8 + lr)*GIN);
          dst = (char*)&Bs[buf][0] + r8*128;
        }
        gload_lds16(src + k0b + bs_sw, dst);
      }
    };

    auto kstep = [&](int kk, int buf){
      const int ko = kk*64 + (lane>>4)*16;
      const int am = 16*w + (lane&15);
      bf16x8 af = *(const bf16x8*)((const char*)&As[buf][0] + am*128 + (ko ^ ((am&7)<<4)));
      #pragma unroll
      for(int t=0;t<8;t++){
        int n = 16*t + (lane&15);
        bf16x8 bf = *(const bf16x8*)((const char*)&Bs[buf][0] + n*128 + (ko ^ ((n&7)<<4)));
        acc[t] = __builtin_amdgcn_mfma_f32_16x16x32_bf16(af, bf, acc[t], 0, 0, 0);
      }
    };

    stage(0,0);
    asm volatile("s_waitcnt vmcnt(0)" ::: "memory");
    __builtin_amdgcn_s_barrier();
    for(int it=0; it<8; it++){
      int buf = it & 1;
      if(it < 7) stage(it+1, buf^1);
      kstep(0, buf);
      kstep(1, buf);
      asm volatile("s_waitcnt vmcnt(0)" ::: "memory");
      __builtin_amdgcn_s_barrier();
    }

    const int mrow = m0 + 16*w + 4*(lane>>4);
    const int nc0  = n0 + (lane&15);
    #pragma unroll
    for(int t=0;t<8;t++){
      #pragma unroll
      for(int r=0;r<4;r++){
        WhbT[(size_t)(mrow + r)*GN + nc0 + 16*t] = (__bf16)acc[t][r];
      }
    }
  } else {
    // ---- Wh1/Wh2 fp32 row-dots (exact-path scores)
    const int row = (bid-2304)*4 + w;
    const float4* hp = (const float4*)(h + (size_t)row*GIN);
    float4 v0 = hp[lane*2], v1 = hp[lane*2+1];
    float4 a0 = ((const float4*)wal)[lane*2], a1 = ((const float4*)wal)[lane*2+1];
    float4 b0 = ((const float4*)war)[lane*2], b1 = ((const float4*)war)[lane*2+1];
    float sl = v0.x*a0.x+v0.y*a0.y+v0.z*a0.z+v0.w*a0.w
             + v1.x*a1.x+v1.y*a1.y+v1.z*a1.z+v1.w*a1.w;
    float sr = v0.x*b0.x+v0.y*b0.y+v0.z*b0.z+v0.w*b0.w
             + v1.x*b1.x+v1.y*b1.y+v1.z*b1.z+v1.w*b1.w;
    #pragma unroll
    for(int of=32;of;of>>=1){ sl += __shfl_down(sl,of,64); sr += __shfl_down(sr,of,64); }
    if(lane==0){ Wh1[row]=sl; Wh2[row]=sr; }
  }
}

// ================= fused masked-softmax-attention =================
// grid 512: rg=bid>>3 (64 rowgroups of 128), chunk=bid&7 (1024 cols; chunk->XCD)
// Masks from pk, prefetched into regs (depth 1). V triple-buffered 32-col panels,
// counted vmcnt(6)/(2) — stage loads get ~2 iters to land, never a full drain.
template<bool PART>
__global__ __launch_bounds__(256,2) void k_attn(const unsigned int* __restrict__ pk,
                                                const __bf16* __restrict__ WhbT,
                                                const float* __restrict__ Wh1s,
                                                const float* __restrict__ Wh2s,
                                                float* __restrict__ pv_out,
                                                float* __restrict__ s_out){
  __shared__ __attribute__((aligned(16))) char Vs[3][16384];
  const int tid = threadIdx.x, lane = tid & 63, w = tid >> 6;
  const int rg = blockIdx.x >> 3, chunk = blockIdx.x & 7;
  const int r0 = rg * 128;
  const int j0 = chunk * 1024;
  const int la = lane & 15, kg = lane >> 4, kg8 = kg << 3;

  f32x4 acc0[16], acc1[16];
  #pragma unroll
  for(int t=0;t<16;t++){ acc0[t] = (f32x4){0.f,0.f,0.f,0.f}; acc1[t] = (f32x4){0.f,0.f,0.f,0.f}; }
  f32x4 accs0 = (f32x4){0.f,0.f,0.f,0.f};
  f32x4 accs1 = (f32x4){0.f,0.f,0.f,0.f};

  bf16x8 ones;
  #pragma unroll
  for(int j=0;j<8;j++) ones[j] = (__bf16)1.0f;

  const int myrow0 = r0 + 16*w + la;
  const float wh1_0 = Wh1s[myrow0];                 // pre-scaled by log2(e)
  const float wh1_1 = Wh1s[myrow0 + 64];

  // per-lane mask pointer: pk[(chunk*32+it)*GN + r0+16w+la] (+64 for set1)
  const unsigned int* pkb = pk + (size_t)(chunk*32)*GN + r0 + 16*w + la;

  // V stage: linear LDS dest, inverse-swizzled global src (same layout as r8)
  const int l_log = (lane&7) ^ (lane>>3);
  const char* wbase = (const char*)WhbT
                    + (size_t)(64*w + 2*(lane>>3) + (l_log>>2))*(GN*2)
                    + (size_t)(l_log&3)*16;

  auto stage = [&](int it, int buf){
    const size_t colb = (size_t)(j0 + it*32)*2;
    char* dst = &Vs[buf][0] + w*4096 + lane*16;
    #pragma unroll
    for(int s=0;s<4;s++){
      gload_lds16(wbase + (size_t)(16*s)*(GN*2) + colb, dst + s*1024);
    }
  };

  unsigned int mr0, mr1, nr0, nr1;
  auto mload = [&](int it, unsigned int& a, unsigned int& b){
    a = pkb[(size_t)it*GN];
    b = pkb[(size_t)it*GN + 64];
  };

  auto mkpa = [&](float wh1, unsigned m8, float4 w0, float4 w1) -> bf16x8 {
    bf16x8 pa;
    float y, p;
    y = wh1 + w0.x; y = fmaxf(y, 0.2f*y); p = exp2f(y); pa[0] = (__bf16)((m8    )&1 ? p : 0.f);
    y = wh1 + w0.y; y = fmaxf(y, 0.2f*y); p = exp2f(y); pa[1] = (__bf16)((m8>>1)&1 ? p : 0.f);
    y = wh1 + w0.z; y = fmaxf(y, 0.2f*y); p = exp2f(y); pa[2] = (__bf16)((m8>>2)&1 ? p : 0.f);
    y = wh1 + w0.w; y = fmaxf(y, 0.2f*y); p = exp2f(y); pa[3] = (__bf16)((m8>>3)&1 ? p : 0.f);
    y = wh1 + w1.x; y = fmaxf(y, 0.2f*y); p = exp2f(y); pa[4] = (__bf16)((m8>>4)&1 ? p : 0.f);
    y = wh1 + w1.y; y = fmaxf(y, 0.2f*y); p = exp2f(y); pa[5] = (__bf16)((m8>>5)&1 ? p : 0.f);
    y = wh1 + w1.z; y = fmaxf(y, 0.2f*y); p = exp2f(y); pa[6] = (__bf16)((m8>>6)&1 ? p : 0.f);
    y = wh1 + w1.w; y = fmaxf(y, 0.2f*y); p = exp2f(y); pa[7] = (__bf16)((m8>>7)&1 ? p : 0.f);
    return pa;
  };

  // per-lane read base into V tile (pair-row + XOR slot), +t*1024 folds to immediate
  const int rd_off = (la>>1)*128 + (((((la&1)<<2) | kg) ^ (la>>1)) << 4);

  auto kstep = [&](int it, int buf){
    const float* wp = Wh2s + j0 + it*32 + kg8;
    float4 w0 = *(const float4*)wp;
    float4 w1 = *(const float4*)(wp + 4);
    bf16x8 pa0 = mkpa(wh1_0, (mr0 >> kg8) & 0xffu, w0, w1);
    bf16x8 pa1 = mkpa(wh1_1, (mr1 >> kg8) & 0xffu, w0, w1);
    const char* vb = &Vs[buf][0] + rd_off;
    #pragma unroll
    for(int t=0;t<16;t++){
      bf16x8 bv = *(const bf16x8*)(vb + t*1024);
      acc0[t] = __builtin_amdgcn_mfma_f32_16x16x32_bf16(pa0, bv, acc0[t], 0, 0, 0);
      acc1[t] = __builtin_amdgcn_mfma_f32_16x16x32_bf16(pa1, bv, acc1[t], 0, 0, 0);
    }
    accs0 = __builtin_amdgcn_mfma_f32_16x16x32_bf16(pa0, ones, accs0, 0, 0, 0);
    accs1 = __builtin_amdgcn_mfma_f32_16x16x32_bf16(pa1, ones, accs1, 0, 0, 0);
  };

  // prologue: mask(0) oldest, then V(0), V(1). vmcnt(4) retires m(0)+s(0), keeps s(1).
  mload(0, mr0, mr1);
  stage(0, 0);
  stage(1, 1);
  asm volatile("s_waitcnt vmcnt(4)" ::: "memory");
  __builtin_amdgcn_s_barrier();

  for(int it=0; it<32; it++){
    const int buf = it % 3;
    if(it < 31) mload(it+1, nr0, nr1);      // mask prefetch (issued before stage: older)
    if(it < 30) stage(it+2, (it+2)%3);      // V prefetch, 2 iters ahead
    kstep(it, buf);
    mr0 = nr0; mr1 = nr1;
    if(it < 30){
      asm volatile("s_waitcnt vmcnt(6)" ::: "memory");   // retire s(it+1); keep m(it+1)+s(it+2)
      __builtin_amdgcn_s_barrier();
    } else if(it == 30){
      asm volatile("s_waitcnt vmcnt(2)" ::: "memory");   // retire s(31); keep m(31)
      __builtin_amdgcn_s_barrier();
    }
  }

  const int orow0 = r0 + 16*w + 4*kg;
  const int orow1 = orow0 + 64;
  const int ocol  = la;
  if constexpr (PART){
    float* pv = pv_out + (size_t)chunk*GN*GOUT;
    float* sp = s_out  + (size_t)chunk*GN;
    #pragma unroll
    for(int t=0;t<16;t++){
      #pragma unroll
      for(int r=0;r<4;r++){
        pv[(size_t)(orow0 + r)*GOUT + ocol + 16*t] = acc0[t][r];
        pv[(size_t)(orow1 + r)*GOUT + ocol + 16*t] = acc1[t][r];
      }
    }
    if(ocol == 0){
      #pragma unroll
      for(int r=0;r<4;r++){ sp[orow0 + r] = accs0[r]; sp[orow1 + r] = accs1[r]; }
    }
  } else {
    #pragma unroll
    for(int t=0;t<16;t++){
      #pragma unroll
      for(int r=0;r<4;r++){
        atomicAdd(pv_out + (size_t)(orow0 + r)*GOUT + ocol + 16*t, acc0[t][r]);
        atomicAdd(pv_out + (size_t)(orow1 + r)*GOUT + ocol + 16*t, acc1[t][r]);
      }
    }
    if(ocol == 0){
      #pragma unroll
      for(int r=0;r<4;r++){ atomicAdd(s_out + orow0 + r, accs0[r]); atomicAdd(s_out + orow1 + r, accs1[r]); }
    }
  }
}

// ---------------- epilogues ----------------
static __device__ __forceinline__ float elu1(float x){
  return x > 0.f ? x : (exp2f(x*LOG2E) - 1.f);
}

__global__ void k_reduce(const float* __restrict__ accP, const float* __restrict__ accSp,
                         float* __restrict__ out){
  size_t i = ((size_t)blockIdx.x*256 + threadIdx.x)*4;
  int row = (int)(i >> 8);
  float S = 0.f;
  #pragma unroll
  for(int c=0;c<8;c++) S += accSp[(size_t)c*GN + row];
  float4 s = {0.f,0.f,0.f,0.f};
  #pragma unroll
  for(int c=0;c<8;c++){
    float4 v = *(const float4*)(accP + (size_t)c*GN*GOUT + i);
    s.x += v.x; s.y += v.y; s.z += v.z; s.w += v.w;
  }
  float inv = 1.0f / S;
  float4 o;
  o.x = elu1(s.x*inv); o.y = elu1(s.y*inv); o.z = elu1(s.z*inv); o.w = elu1(s.w*inv);
  *(float4*)(out + i) = o;
}

__global__ void k_norm(const float* __restrict__ accPV, const float* __restrict__ accS,
                       float* __restrict__ out){
  size_t i = ((size_t)blockIdx.x*256 + threadIdx.x)*4;
  int row = (int)(i >> 8);
  float inv = 1.0f / accS[row];
  float4 v = *(const float4*)(accPV + i);
  float4 o;
  o.x = elu1(v.x*inv); o.y = elu1(v.y*inv); o.z = elu1(v.z*inv); o.w = elu1(v.w*inv);
  *(float4*)(out + i) = o;
}

// ---------------- launch ----------------
extern "C" void kernel_launch(void* const* d_in, const int* in_sizes, int n_in,
                              void* d_out, int out_size, void* d_ws, size_t ws_size,
                              hipStream_t stream){
  const float* h  = (const float*)d_in[0];
  const int*   adj= (const int*)  d_in[1];
  const float* W  = (const float*)d_in[2];
  const float* al = (const float*)d_in[3];
  const float* ar = (const float*)d_in[4];
  float* out = (float*)d_out;
  char* ws = (char*)d_ws;

  const size_t SZ_ACCP = (size_t)8*GN*GOUT*4;        // 67,108,864
  const size_t SZ_PK   = (size_t)256*GN*4;           //  8,388,608
  const size_t NEED_A  = SZ_ACCP + 4194304 + 32768 + 32768 + 262144 + SZ_PK;

  if(ws_size >= NEED_A){
    float*  accP  = (float*) (ws);
    __bf16* hb    = (__bf16*)(ws);                       // alias (prep-only)
    __bf16* WT    = (__bf16*)(ws + 8388608);             // alias (prep-only)
    float*  wal   = (float*) (ws + 8650752);             // alias (prep-only)
    float*  war   = (float*) (ws + 8652800);             // alias (prep-only)
    __bf16* WhbT  = (__bf16*)(ws + SZ_ACCP);
    float*  Wh1   = (float*) (ws + SZ_ACCP + 4194304);
    float*  Wh2   = (float*) (ws + SZ_ACCP + 4227072);
    float*  accSp = (float*) (ws + SZ_ACCP + 4259840);
    unsigned int* pk = (unsigned int*)(ws + SZ_ACCP + 4521984);

    k_pre1<<<2208, 256, 0, stream>>>(W, al, ar, h, wal, war, WT, hb);
    k_pre2<<<4352, 256, 0, stream>>>(adj, pk, WT, hb, WhbT, h, wal, war, Wh1, Wh2);
    k_attn<true><<<512, 256, 0, stream>>>(pk, WhbT, Wh1, Wh2, accP, accSp);
    k_reduce<<<2048, 256, 0, stream>>>(accP, accSp, out);
  } else {
    float*  accPV = (float*) (ws);                       //  8,388,608
    float*  accS  = (float*) (ws + 8388608);             //     32,768
    __bf16* hb    = (__bf16*)(ws + 8421376);             //  8,388,608
    __bf16* WT    = (__bf16*)(ws + 16809984);            //    262,144
    __bf16* WhbT  = (__bf16*)(ws + 17072128);            //  4,194,304
    float*  wal   = (float*) (ws + 21266432);
    float*  war   = (float*) (ws + 21268480);
    float*  Wh1   = (float*) (ws + 21270528);
    float*  Wh2   = (float*) (ws + 21303296);
    unsigned int* pk = (unsigned int*)(ws + 21336064);
    if(ws_size < 21336064 + SZ_PK) return;

    hipMemsetAsync(accPV, 0, 8388608 + 32768, stream);
    k_pre1<<<2208, 256, 0, stream>>>(W, al, ar, h, wal, war, WT, hb);
    k_pre2<<<4352, 256, 0, stream>>>(adj, pk, WT, hb, WhbT, h, wal, war, Wh1, Wh2);
    k_attn<false><<<512, 256, 0, stream>>>(pk, WhbT, Wh1, Wh2, accPV, accS);
    k_norm<<<2048, 256, 0, stream>>>(accPV, accS, out);
  }
}

// Round 10
// 141.457 us; speedup vs baseline: 13.2700x; 1.0225x over previous
//
#include <hip/hip_runtime.h>
#include <hip/hip_bf16.h>
#include <cstdint>
#include <cstddef>

typedef float  f32x4  __attribute__((ext_vector_type(4)));
typedef __bf16 bf16x8 __attribute__((ext_vector_type(8)));

#define LOG2E 1.4426950408889634f

static constexpr int GN   = 8192;   // nodes
static constexpr int GIN  = 512;    // in features
static constexpr int GOUT = 256;    // out features

// ---------------- async global->LDS (width 16) ----------------
static __device__ __forceinline__ void gload_lds16(const void* g, void* lds){
  typedef uint32_t __attribute__((address_space(1)))* gp_t;
  typedef uint32_t __attribute__((address_space(3)))* lp_t;
  __builtin_amdgcn_global_load_lds((gp_t)(uintptr_t)g,
                                   (lp_t)(uint32_t)(uintptr_t)lds, 16, 0, 0);
}

// ================= L1: [wal/war: 128 blk][W-transpose: 32 blk][h->bf16: 2048 blk] ====
__global__ __launch_bounds__(256) void k_pre1(const float* __restrict__ W,
                                              const float* __restrict__ al,
                                              const float* __restrict__ ar,
                                              const float* __restrict__ h,
                                              float* __restrict__ wal,
                                              float* __restrict__ war,
                                              __bf16* __restrict__ WT,
                                              __bf16* __restrict__ hb){
  __shared__ float T[64][65];
  const int bid = blockIdx.x, tid = threadIdx.x;
  if(bid < 128){
    const int k = bid*4 + (tid>>6), lane = tid & 63;
    float4 wv = ((const float4*)(W + (size_t)k*GOUT))[lane];
    float4 av = ((const float4*)al)[lane];
    float4 bv = ((const float4*)ar)[lane];
    float sl = wv.x*av.x + wv.y*av.y + wv.z*av.z + wv.w*av.w;
    float sr = wv.x*bv.x + wv.y*bv.y + wv.z*bv.z + wv.w*bv.w;
    #pragma unroll
    for(int o=32;o;o>>=1){ sl += __shfl_down(sl,o,64); sr += __shfl_down(sr,o,64); }
    if(lane==0){ wal[k] = sl*LOG2E; war[k] = sr*LOG2E; }
  } else if(bid < 160){
    const int tile = bid - 128;
    const int k0 = (tile>>2)*64, c0 = (tile&3)*64;
    const int r = tid>>2, cs = (tid&3)*16;
    #pragma unroll
    for(int j=0;j<4;j++){
      float4 v = *(const float4*)(W + (size_t)(k0+r)*GOUT + c0 + cs + 4*j);
      T[r][cs+4*j+0]=v.x; T[r][cs+4*j+1]=v.y; T[r][cs+4*j+2]=v.z; T[r][cs+4*j+3]=v.w;
    }
    __syncthreads();
    bf16x8 o1, o2;
    #pragma unroll
    for(int j=0;j<8;j++){ o1[j]=(__bf16)T[cs+j][r]; o2[j]=(__bf16)T[cs+8+j][r]; }
    __bf16* dst = WT + (size_t)(c0+r)*GIN + k0 + cs;
    *(bf16x8*)dst = o1;
    *(bf16x8*)(dst+8) = o2;
  } else {
    size_t i = ((size_t)(bid-160)*256 + tid)*8;
    float4 v0 = *(const float4*)(h+i);
    float4 v1 = *(const float4*)(h+i+4);
    bf16x8 o;
    o[0]=(__bf16)v0.x; o[1]=(__bf16)v0.y; o[2]=(__bf16)v0.z; o[3]=(__bf16)v0.w;
    o[4]=(__bf16)v1.x; o[5]=(__bf16)v1.y; o[6]=(__bf16)v1.z; o[7]=(__bf16)v1.w;
    *(bf16x8*)(hb+i) = o;
  }
}

// ================= L2 mega: [pack: 2048][gemmT: 256][Wh12: 2048] — independent roles
__global__ __launch_bounds__(256) void k_pre2(const int* __restrict__ adj,
                                              unsigned int* __restrict__ pk,
                                              const __bf16* __restrict__ WT,
                                              const __bf16* __restrict__ hb,
                                              __bf16* __restrict__ WhbT,
                                              const float* __restrict__ h,
                                              const float* __restrict__ wal,
                                              const float* __restrict__ war,
                                              float* __restrict__ Wh1,
                                              float* __restrict__ Wh2){
  __shared__ __attribute__((aligned(16))) __bf16 As[2][64*64];
  __shared__ __attribute__((aligned(16))) __bf16 Bs[2][128*64];
  const int bid = blockIdx.x, tid = threadIdx.x;
  const int lane = tid & 63, w = tid >> 6;

  if(bid < 2048){
    // ---- pack: adj -> bitmask pk[j32][row]
    const int Wv = bid*4 + w;
    const int jb = Wv & 127;
    const int g  = Wv >> 7;
    const size_t cb = (size_t)jb*64 + lane;
    const int idx = lane & 15;
    #pragma unroll 1
    for(int i=0;i<8;i++){
      const int r0 = (g*8 + i)*16;
      int a[16];
      #pragma unroll
      for(int r=0;r<16;r++) a[r] = adj[(size_t)(r0+r)*GN + cb];
      uint64_t b0 = __ballot(a[0]!=0),  b1 = __ballot(a[1]!=0);
      uint64_t b2 = __ballot(a[2]!=0),  b3 = __ballot(a[3]!=0);
      uint64_t b4 = __ballot(a[4]!=0),  b5 = __ballot(a[5]!=0);
      uint64_t b6 = __ballot(a[6]!=0),  b7 = __ballot(a[7]!=0);
      uint64_t b8 = __ballot(a[8]!=0),  b9 = __ballot(a[9]!=0);
      uint64_t bA = __ballot(a[10]!=0), bB = __ballot(a[11]!=0);
      uint64_t bC = __ballot(a[12]!=0), bD = __ballot(a[13]!=0);
      uint64_t bE = __ballot(a[14]!=0), bF = __ballot(a[15]!=0);
      uint64_t c0 = (idx&1)? b1:b0, c1 = (idx&1)? b3:b2;
      uint64_t c2 = (idx&1)? b5:b4, c3 = (idx&1)? b7:b6;
      uint64_t c4 = (idx&1)? b9:b8, c5 = (idx&1)? bB:bA;
      uint64_t c6 = (idx&1)? bD:bC, c7 = (idx&1)? bF:bE;
      uint64_t d0 = (idx&2)? c1:c0, d1 = (idx&2)? c3:c2;
      uint64_t d2 = (idx&2)? c5:c4, d3 = (idx&2)? c7:c6;
      uint64_t e0 = (idx&4)? d1:d0, e1 = (idx&4)? d3:d2;
      uint64_t v  = (idx&8)? e1:e0;
      unsigned int hword = (lane&16)? (unsigned int)(v>>32) : (unsigned int)v;
      if(lane < 32){
        pk[(size_t)(2*jb + (lane>>4))*GN + r0 + idx] = hword;
      }
    }
  } else if(bid < 2304){
    // ---- gemmT
    const int b2 = bid - 2048;
    const int mb = b2 >> 6, nb = b2 & 63;
    const int m0 = mb*64, n0 = nb*128;

    f32x4 acc[8];
    #pragma unroll
    for(int t=0;t<8;t++) acc[t] = (f32x4){0.f,0.f,0.f,0.f};

    const int lr = lane>>3;
    const int bs_sw = ((lane&7)*16) ^ (lr<<4);

    auto stage = [&](int it, int buf){
      const int k0b = it*128;
      #pragma unroll
      for(int s=0;s<6;s++){
        int u = w + s*4;
        const char* src; char* dst;
        if(u < 8){
          int r8 = u*8;
          src = (const char*)(WT + (size_t)(m0 + r8 + lr)*GIN);
          dst = (char*)&As[buf][0] + r8*128;
        } else {
          int r8 = (u-8)*8;
          src = (const char*)(hb + (size_t)(n0 + r8 + lr)*GIN);
          dst = (char*)&Bs[buf][0] + r8*128;
        }
        gload_lds16(src + k0b + bs_sw, dst);
      }
    };

    auto kstep = [&](int kk, int buf){
      const int ko = kk*64 + (lane>>4)*16;
      const int am = 16*w + (lane&15);
      bf16x8 af = *(const bf16x8*)((const char*)&As[buf][0] + am*128 + (ko ^ ((am&7)<<4)));
      #pragma unroll
      for(int t=0;t<8;t++){
        int n = 16*t + (lane&15);
        bf16x8 bf = *(const bf16x8*)((const char*)&Bs[buf][0] + n*128 + (ko ^ ((n&7)<<4)));
        acc[t] = __builtin_amdgcn_mfma_f32_16x16x32_bf16(af, bf, acc[t], 0, 0, 0);
      }
    };

    stage(0,0);
    asm volatile("s_waitcnt vmcnt(0)" ::: "memory");
    __builtin_amdgcn_s_barrier();
    for(int it=0; it<8; it++){
      int buf = it & 1;
      if(it < 7) stage(it+1, buf^1);
      kstep(0, buf);
      kstep(1, buf);
      asm volatile("s_waitcnt vmcnt(0)" ::: "memory");
      __builtin_amdgcn_s_barrier();
    }

    const int mrow = m0 + 16*w + 4*(lane>>4);
    const int nc0  = n0 + (lane&15);
    #pragma unroll
    for(int t=0;t<8;t++){
      #pragma unroll
      for(int r=0;r<4;r++){
        WhbT[(size_t)(mrow + r)*GN + nc0 + 16*t] = (__bf16)acc[t][r];
      }
    }
  } else {
    // ---- Wh1/Wh2 fp32 row-dots
    const int row = (bid-2304)*4 + w;
    const float4* hp = (const float4*)(h + (size_t)row*GIN);
    float4 v0 = hp[lane*2], v1 = hp[lane*2+1];
    float4 a0 = ((const float4*)wal)[lane*2], a1 = ((const float4*)wal)[lane*2+1];
    float4 b0 = ((const float4*)war)[lane*2], b1 = ((const float4*)war)[lane*2+1];
    float sl = v0.x*a0.x+v0.y*a0.y+v0.z*a0.z+v0.w*a0.w
             + v1.x*a1.x+v1.y*a1.y+v1.z*a1.z+v1.w*a1.w;
    float sr = v0.x*b0.x+v0.y*b0.y+v0.z*b0.z+v0.w*b0.w
             + v1.x*b1.x+v1.y*b1.y+v1.z*b1.z+v1.w*b1.w;
    #pragma unroll
    for(int of=32;of;of>>=1){ sl += __shfl_down(sl,of,64); sr += __shfl_down(sr,of,64); }
    if(lane==0){ Wh1[row]=sl; Wh2[row]=sr; }
  }
}

// ================= fused masked-softmax-attention (zero global consumes in loop) ====
// grid 512: rg=bid>>3 (64 rowgroups of 128), chunk=bid&7 (1024 cols; chunk->XCD).
// Masks (16KB) + Wh2 strip (4KB) staged to LDS ONCE in prologue (reg-loads issued
// BEFORE stage(0) so their consume can't drain it). Inner loop's only VM ops are the
// 4 async gload_lds — vmcnt(0) at the bottom retires loads issued a full kstep ago.
template<bool PART>
__global__ __launch_bounds__(256,2) void k_attn(const unsigned int* __restrict__ pk,
                                                const __bf16* __restrict__ WhbT,
                                                const float* __restrict__ Wh1s,
                                                const float* __restrict__ Wh2s,
                                                float* __restrict__ pv_out,
                                                float* __restrict__ s_out){
  __shared__ __attribute__((aligned(16))) char Vs[2][16384];
  __shared__ __attribute__((aligned(16))) unsigned int mkL[32*128];
  __shared__ __attribute__((aligned(16))) float wh2L[1024];
  const int tid = threadIdx.x, lane = tid & 63, w = tid >> 6;
  const int rg = blockIdx.x >> 3, chunk = blockIdx.x & 7;
  const int r0 = rg * 128;
  const int j0 = chunk * 1024;
  const int la = lane & 15, kg = lane >> 4, kg8 = kg << 3;

  // ---- prologue reg-loads (masks + wh2 + wh1) issued BEFORE stage(0) ----
  const int jrow = tid >> 5, c4 = (tid & 31) * 4;
  uint4 mv0 = *(const uint4*)(pk + (size_t)(chunk*32 +  0 + jrow)*GN + r0 + c4);
  uint4 mv1 = *(const uint4*)(pk + (size_t)(chunk*32 +  8 + jrow)*GN + r0 + c4);
  uint4 mv2 = *(const uint4*)(pk + (size_t)(chunk*32 + 16 + jrow)*GN + r0 + c4);
  uint4 mv3 = *(const uint4*)(pk + (size_t)(chunk*32 + 24 + jrow)*GN + r0 + c4);
  float4 wv = *(const float4*)(Wh2s + j0 + tid*4);
  const float wh1_0 = Wh1s[r0 + 16*w + la];        // pre-scaled by log2(e)
  const float wh1_1 = Wh1s[r0 + 16*w + la + 64];

  // V stage: linear LDS dest, inverse-swizzled global src (r9 layout, verified)
  const int l_log = (lane&7) ^ (lane>>3);
  const char* wbase = (const char*)WhbT
                    + (size_t)(64*w + 2*(lane>>3) + (l_log>>2))*(GN*2)
                    + (size_t)(l_log&3)*16;
  auto stage = [&](int it, int buf){
    const size_t colb = (size_t)(j0 + it*32)*2;
    char* dst = &Vs[buf][0] + w*4096 + lane*16;
    #pragma unroll
    for(int s=0;s<4;s++){
      gload_lds16(wbase + (size_t)(16*s)*(GN*2) + colb, dst + s*1024);
    }
  };

  stage(0, 0);                       // in flight across the LDS fills below

  *(uint4*)&mkL[( 0 + jrow)*128 + c4] = mv0;
  *(uint4*)&mkL[( 8 + jrow)*128 + c4] = mv1;
  *(uint4*)&mkL[(16 + jrow)*128 + c4] = mv2;
  *(uint4*)&mkL[(24 + jrow)*128 + c4] = mv3;
  *(float4*)&wh2L[tid*4] = wv;

  f32x4 acc0[16], acc1[16];
  #pragma unroll
  for(int t=0;t<16;t++){ acc0[t] = (f32x4){0.f,0.f,0.f,0.f}; acc1[t] = (f32x4){0.f,0.f,0.f,0.f}; }
  f32x4 accs0 = (f32x4){0.f,0.f,0.f,0.f};
  f32x4 accs1 = (f32x4){0.f,0.f,0.f,0.f};
  bf16x8 ones;
  #pragma unroll
  for(int j=0;j<8;j++) ones[j] = (__bf16)1.0f;

  __syncthreads();                   // drains stage(0) + LDS fills

  auto mkpa = [&](float wh1, unsigned m8, float4 w0, float4 w1) -> bf16x8 {
    bf16x8 pa;
    float y, p;
    y = wh1 + w0.x; y = fmaxf(y, 0.2f*y); p = exp2f(y); pa[0] = (__bf16)((m8    )&1 ? p : 0.f);
    y = wh1 + w0.y; y = fmaxf(y, 0.2f*y); p = exp2f(y); pa[1] = (__bf16)((m8>>1)&1 ? p : 0.f);
    y = wh1 + w0.z; y = fmaxf(y, 0.2f*y); p = exp2f(y); pa[2] = (__bf16)((m8>>2)&1 ? p : 0.f);
    y = wh1 + w0.w; y = fmaxf(y, 0.2f*y); p = exp2f(y); pa[3] = (__bf16)((m8>>3)&1 ? p : 0.f);
    y = wh1 + w1.x; y = fmaxf(y, 0.2f*y); p = exp2f(y); pa[4] = (__bf16)((m8>>4)&1 ? p : 0.f);
    y = wh1 + w1.y; y = fmaxf(y, 0.2f*y); p = exp2f(y); pa[5] = (__bf16)((m8>>5)&1 ? p : 0.f);
    y = wh1 + w1.z; y = fmaxf(y, 0.2f*y); p = exp2f(y); pa[6] = (__bf16)((m8>>6)&1 ? p : 0.f);
    y = wh1 + w1.w; y = fmaxf(y, 0.2f*y); p = exp2f(y); pa[7] = (__bf16)((m8>>7)&1 ? p : 0.f);
    return pa;
  };

  // per-lane read base into V tile (pair-row + XOR slot), +t*1024 folds to immediate
  const int rd_off = (la>>1)*128 + (((((la&1)<<2) | kg) ^ (la>>1)) << 4);

  auto kstep = [&](int it, int buf){
    unsigned int m0 = mkL[it*128 + 16*w + la];
    unsigned int m1 = mkL[it*128 + 16*w + la + 64];
    const float* wp = &wh2L[it*32 + kg8];
    float4 w0 = *(const float4*)wp;
    float4 w1 = *(const float4*)(wp + 4);
    bf16x8 pa0 = mkpa(wh1_0, (m0 >> kg8) & 0xffu, w0, w1);
    bf16x8 pa1 = mkpa(wh1_1, (m1 >> kg8) & 0xffu, w0, w1);
    const char* vb = &Vs[buf][0] + rd_off;
    #pragma unroll
    for(int t=0;t<16;t++){
      bf16x8 bv = *(const bf16x8*)(vb + t*1024);
      acc0[t] = __builtin_amdgcn_mfma_f32_16x16x32_bf16(pa0, bv, acc0[t], 0, 0, 0);
      acc1[t] = __builtin_amdgcn_mfma_f32_16x16x32_bf16(pa1, bv, acc1[t], 0, 0, 0);
    }
    accs0 = __builtin_amdgcn_mfma_f32_16x16x32_bf16(pa0, ones, accs0, 0, 0, 0);
    accs1 = __builtin_amdgcn_mfma_f32_16x16x32_bf16(pa1, ones, accs1, 0, 0, 0);
  };

  for(int it=0; it<32; it++){
    const int buf = it & 1;
    if(it < 31) stage(it+1, buf^1);    // only VM ops in the loop; async, never consumed
    kstep(it, buf);                    // pure LDS + VALU + MFMA
    asm volatile("s_waitcnt vmcnt(0)" ::: "memory");   // stage had a full kstep to land
    __builtin_amdgcn_s_barrier();
  }

  const int orow0 = r0 + 16*w + 4*kg;
  const int orow1 = orow0 + 64;
  const int ocol  = la;
  if constexpr (PART){
    float* pv = pv_out + (size_t)chunk*GN*GOUT;
    float* sp = s_out  + (size_t)chunk*GN;
    #pragma unroll
    for(int t=0;t<16;t++){
      #pragma unroll
      for(int r=0;r<4;r++){
        pv[(size_t)(orow0 + r)*GOUT + ocol + 16*t] = acc0[t][r];
        pv[(size_t)(orow1 + r)*GOUT + ocol + 16*t] = acc1[t][r];
      }
    }
    if(ocol == 0){
      #pragma unroll
      for(int r=0;r<4;r++){ sp[orow0 + r] = accs0[r]; sp[orow1 + r] = accs1[r]; }
    }
  } else {
    #pragma unroll
    for(int t=0;t<16;t++){
      #pragma unroll
      for(int r=0;r<4;r++){
        atomicAdd(pv_out + (size_t)(orow0 + r)*GOUT + ocol + 16*t, acc0[t][r]);
        atomicAdd(pv_out + (size_t)(orow1 + r)*GOUT + ocol + 16*t, acc1[t][r]);
      }
    }
    if(ocol == 0){
      #pragma unroll
      for(int r=0;r<4;r++){ atomicAdd(s_out + orow0 + r, accs0[r]); atomicAdd(s_out + orow1 + r, accs1[r]); }
    }
  }
}

// ---------------- epilogues ----------------
static __device__ __forceinline__ float elu1(float x){
  return x > 0.f ? x : (exp2f(x*LOG2E) - 1.f);
}

__global__ void k_reduce(const float* __restrict__ accP, const float* __restrict__ accSp,
                         float* __restrict__ out){
  size_t i = ((size_t)blockIdx.x*256 + threadIdx.x)*4;
  int row = (int)(i >> 8);
  float S = 0.f;
  #pragma unroll
  for(int c=0;c<8;c++) S += accSp[(size_t)c*GN + row];
  float4 s = {0.f,0.f,0.f,0.f};
  #pragma unroll
  for(int c=0;c<8;c++){
    float4 v = *(const float4*)(accP + (size_t)c*GN*GOUT + i);
    s.x += v.x; s.y += v.y; s.z += v.z; s.w += v.w;
  }
  float inv = 1.0f / S;
  float4 o;
  o.x = elu1(s.x*inv); o.y = elu1(s.y*inv); o.z = elu1(s.z*inv); o.w = elu1(s.w*inv);
  *(float4*)(out + i) = o;
}

__global__ void k_norm(const float* __restrict__ accPV, const float* __restrict__ accS,
                       float* __restrict__ out){
  size_t i = ((size_t)blockIdx.x*256 + threadIdx.x)*4;
  int row = (int)(i >> 8);
  float inv = 1.0f / accS[row];
  float4 v = *(const float4*)(accPV + i);
  float4 o;
  o.x = elu1(v.x*inv); o.y = elu1(v.y*inv); o.z = elu1(v.z*inv); o.w = elu1(v.w*inv);
  *(float4*)(out + i) = o;
}

// ---------------- launch ----------------
extern "C" void kernel_launch(void* const* d_in, const int* in_sizes, int n_in,
                              void* d_out, int out_size, void* d_ws, size_t ws_size,
                              hipStream_t stream){
  const float* h  = (const float*)d_in[0];
  const int*   adj= (const int*)  d_in[1];
  const float* W  = (const float*)d_in[2];
  const float* al = (const float*)d_in[3];
  const float* ar = (const float*)d_in[4];
  float* out = (float*)d_out;
  char* ws = (char*)d_ws;

  const size_t SZ_ACCP = (size_t)8*GN*GOUT*4;        // 67,108,864
  const size_t SZ_PK   = (size_t)256*GN*4;           //  8,388,608
  const size_t NEED_A  = SZ_ACCP + 4194304 + 32768 + 32768 + 262144 + SZ_PK;

  if(ws_size >= NEED_A){
    float*  accP  = (float*) (ws);
    __bf16* hb    = (__bf16*)(ws);                       // alias (prep-only)
    __bf16* WT    = (__bf16*)(ws + 8388608);             // alias (prep-only)
    float*  wal   = (float*) (ws + 8650752);             // alias (prep-only)
    float*  war   = (float*) (ws + 8652800);             // alias (prep-only)
    __bf16* WhbT  = (__bf16*)(ws + SZ_ACCP);
    float*  Wh1   = (float*) (ws + SZ_ACCP + 4194304);
    float*  Wh2   = (float*) (ws + SZ_ACCP + 4227072);
    float*  accSp = (float*) (ws + SZ_ACCP + 4259840);
    unsigned int* pk = (unsigned int*)(ws + SZ_ACCP + 4521984);

    k_pre1<<<2208, 256, 0, stream>>>(W, al, ar, h, wal, war, WT, hb);
    k_pre2<<<4352, 256, 0, stream>>>(adj, pk, WT, hb, WhbT, h, wal, war, Wh1, Wh2);
    k_attn<true><<<512, 256, 0, stream>>>(pk, WhbT, Wh1, Wh2, accP, accSp);
    k_reduce<<<2048, 256, 0, stream>>>(accP, accSp, out);
  } else {
    float*  accPV = (float*) (ws);                       //  8,388,608
    float*  accS  = (float*) (ws + 8388608);             //     32,768
    __bf16* hb    = (__bf16*)(ws + 8421376);             //  8,388,608
    __bf16* WT    = (__bf16*)(ws + 16809984);            //    262,144
    __bf16* WhbT  = (__bf16*)(ws + 17072128);            //  4,194,304
    float*  wal   = (float*) (ws + 21266432);
    float*  war   = (float*) (ws + 21268480);
    float*  Wh1   = (float*) (ws + 21270528);
    float*  Wh2   = (float*) (ws + 21303296);
    unsigned int* pk = (unsigned int*)(ws + 21336064);
    if(ws_size < 21336064 + SZ_PK) return;

    hipMemsetAsync(accPV, 0, 8388608 + 32768, stream);
    k_pre1<<<2208, 256, 0, stream>>>(W, al, ar, h, wal, war, WT, hb);
    k_pre2<<<4352, 256, 0, stream>>>(adj, pk, WT, hb, WhbT, h, wal, war, Wh1, Wh2);
    k_attn<false><<<512, 256, 0, stream>>>(pk, WhbT, Wh1, Wh2, accPV, accS);
    k_norm<<<2048, 256, 0, stream>>>(accPV, accS, out);
  }
}